// Round 8
// baseline (186.877 us; speedup 1.0000x reference)
//
#include <hip/hip_runtime.h>
#include <math.h>

// B=2, Lq=1024, C=256, H=W=64 -> Lk=4096, NC=2, NH=8, D=32.
// R8: attention reworked to 32 q-rows/wave (2 q-frags; K/V frags reused
// across both) -> blocks 2048->1024, K/V staging traffic halved. Rest of
// the 5-kernel pipeline unchanged from R7.

#define LQ 1024
#define HW 4096
#define LOG2E 1.4426950408889634f

typedef __attribute__((ext_vector_type(8))) short short8;
typedef __attribute__((ext_vector_type(4))) float f32x4;
typedef unsigned short u16;

__device__ __forceinline__ u16 bf16r(float x) {
    unsigned int u = __float_as_uint(x);
    u = (u + 0x7FFFu + ((u >> 16) & 1u)) >> 16;
    return (u16)u;
}

__device__ __forceinline__ float b2f(u16 v) {
    return __uint_as_float((unsigned)v << 16);
}

__device__ __forceinline__ float ent2(float a, float b) {
    float m  = fmaxf(a, b);
    float e0 = expf(a - m), e1 = expf(b - m);
    float iz = 1.f / (e0 + e1);
    float p0 = fmaxf(e0 * iz, 1e-8f);
    float p1 = fmaxf(e1 * iz, 1e-8f);
    return -(p0 * logf(p0) + p1 * logf(p1));
}

typedef __attribute__((address_space(1))) const unsigned int gas_u32;
typedef __attribute__((address_space(3))) unsigned int las_u32;
__device__ __forceinline__ void glds16(const void* g, void* l) {
    __builtin_amdgcn_global_load_lds((gas_u32*)g, (las_u32*)l, 16, 0, 0);
}

// ---- device MFMA GEMM core: 32 rows x 128 cols per bid-pair (4 waves).
// EPI: 0 none, 3 *scale. OUT bf16.
template <int EPI>
__device__ __forceinline__ void mgemm_dev(int bid, const u16* __restrict__ A,
                                          const u16* __restrict__ Wt,
                                          const float* __restrict__ bias,
                                          float scale, u16* __restrict__ out16) {
    const int wv = threadIdx.x >> 6, lane = threadIdx.x & 63;
    const int lm = lane & 15, quad = lane >> 4;
    const int row0 = (bid >> 1) * 32;
    const int c0 = (bid & 1) * 128 + wv * 32;
    short8 af[2][8];
#pragma unroll
    for (int s = 0; s < 2; ++s)
#pragma unroll
        for (int i = 0; i < 8; ++i)
            af[s][i] = *(const short8*)(A + (size_t)(row0 + s * 16 + lm) * 256 +
                                        i * 32 + quad * 8);
    f32x4 acc[2][2];
#pragma unroll
    for (int j = 0; j < 2; ++j) {
        float bv = bias ? bias[c0 + j * 16 + lm] : 0.f;
        acc[0][j] = f32x4{bv, bv, bv, bv};
        acc[1][j] = acc[0][j];
    }
#pragma unroll
    for (int j = 0; j < 2; ++j) {
        const u16* wp = Wt + (size_t)(c0 + j * 16 + lm) * 256 + quad * 8;
#pragma unroll
        for (int i = 0; i < 8; ++i) {
            short8 bf = *(const short8*)(wp + i * 32);
#pragma unroll
            for (int s = 0; s < 2; ++s)
                acc[s][j] = __builtin_amdgcn_mfma_f32_16x16x32_bf16(af[s][i], bf,
                                                                    acc[s][j], 0, 0, 0);
        }
    }
#pragma unroll
    for (int s = 0; s < 2; ++s)
#pragma unroll
        for (int j = 0; j < 2; ++j) {
            int n = c0 + j * 16 + lm;
#pragma unroll
            for (int r = 0; r < 4; ++r) {
                int row = row0 + s * 16 + quad * 4 + r;
                float v = acc[s][j][r];
                if (EPI == 3) v *= scale;
                out16[(size_t)row * 256 + n] = bf16r(v);
            }
        }
}

// ======== K1: prep. [0,576) weights, [576,578) bias_fuse, [578,610) mean partials
__global__ __launch_bounds__(256) void k1_prep(
    const float* qpW1hi, const float* Wk, const float* Wv, const float* phiQ1,
    const float* Wq, const float* phiW, const float* phiQ2, const float* Wo,
    u16* qpW1loT, u16* WkT, u16* WvT, u16* phiQ1T, u16* WqT, u16* phiWT,
    u16* phiQ2s, u16* Wos,
    const float* pb2, const float* bq, const float* bo, const float* phib,
    float* bf1, float* bf2,
    const float* S_SM, float* spart) {
    __shared__ float tile[32][33];
    int bid = blockIdx.x;
    if (bid < 576) {
        if (bid >= 448) {  // straight bf16 converts of phiQ2, Wo
            int b2 = bid - 448;
            const float* S = (b2 < 64) ? phiQ2 : Wo;
            u16* D = (b2 < 64) ? phiQ2s : Wos;
            int idx = ((b2 & 63) * 256 + threadIdx.x) * 4;
            float4 v = *(const float4*)&S[idx];
            ushort4 pk = {bf16r(v.x), bf16r(v.y), bf16r(v.z), bf16r(v.w)};
            *(ushort4*)&D[idx] = pk;
            return;
        }
        const float* S; u16* D; int K;
        if (bid < 64)       { S = qpW1hi; D = qpW1loT; K = 256; }
        else if (bid < 128) { S = Wk; D = WkT; K = 256; bid -= 64; }
        else if (bid < 192) { S = Wv; D = WvT; K = 256; bid -= 128; }
        else if (bid < 320) { S = phiQ1; D = phiQ1T; K = 512; bid -= 192; }
        else if (bid < 384) { S = Wq; D = WqT; K = 256; bid -= 320; }
        else                { S = phiW; D = phiWT; K = 256; bid -= 384; }
        int KT = K >> 5;
        int tk = bid % KT, tn = bid / KT;
        int cc = threadIdx.x & 31, rb = threadIdx.x >> 5;
#pragma unroll
        for (int i = 0; i < 4; ++i) {
            int rr = rb + i * 8;
            tile[rr][cc] = S[(size_t)(tk * 32 + rr) * 256 + tn * 32 + cc];
        }
        __syncthreads();
#pragma unroll
        for (int i = 0; i < 4; ++i) {
            int rr = rb + i * 8;
            D[(size_t)(tn * 32 + rr) * K + tk * 32 + cc] = bf16r(tile[cc][rr]);
        }
    } else if (bid < 578) {  // bias_fuse
        int n = threadIdx.x;
        if (bid == 576) {
            float a = bq[n];
            for (int c = 0; c < 256; ++c) a += pb2[c] * Wq[c * 256 + n];
            bf1[n] = a;
        } else {
            float a = phib[n];
            for (int c = 0; c < 256; ++c) a += bo[c] * phiW[c * 256 + n];
            bf2[n] = a;
        }
    } else {  // mean partials
        int bi = bid - 578;
        int b = bi >> 4, l0 = (bi & 15) * 64;
        int c = threadIdx.x;
        const float* p = S_SM + (size_t)b * LQ * 256 + (size_t)l0 * 256 + c;
        float acc = 0.f;
#pragma unroll 8
        for (int l = 0; l < 64; ++l) acc += p[(size_t)l * 256];
        spart[bi * 256 + c] = acc;
    }
}

// ======== K2: mid. [0,2) sbias, [2,18) Wf1T, [18,34) Wf2T, [34,290) phiQ1
__global__ __launch_bounds__(256) void k2_mid(
    const float* spart, const float* qpW1, const float* qpb1, float* sb,
    const u16* WqT, const u16* phiQ2s, u16* Wf1T,
    const u16* phiWT, const u16* Wos, u16* Wf2T,
    const float* S_QP, const float* S_SM, const u16* phiQ1T,
    const float* phiQb1, u16* Qmid) {
    __shared__ float s_s[256];
    int bid = blockIdx.x;
    if (bid < 2) {  // sbias
        int b = bid, o = threadIdx.x;
        float sm = 0.f;
#pragma unroll
        for (int p = 0; p < 16; ++p) sm += spart[(b * 16 + p) * 256 + o];
        s_s[o] = sm * (1.f / 1024.f);
        __syncthreads();
        float acc = qpb1[o];
        for (int c = 0; c < 256; ++c) acc += s_s[c] * qpW1[c * 256 + o];
        sb[b * 256 + o] = acc;
    } else if (bid < 18) {
        mgemm_dev<0>(bid - 2, WqT, phiQ2s, nullptr, 0.f, Wf1T);
    } else if (bid < 34) {
        mgemm_dev<0>(bid - 18, phiWT, Wos, nullptr, 0.f, Wf2T);
    } else {  // phiQ1: relu([S_QP|S_SM] @ phiQ1T^T + b1) -> Qmid bf16
        int b2 = bid - 34;
        const int wv = threadIdx.x >> 6, lane = threadIdx.x & 63;
        const int lm = lane & 15, quad = lane >> 4;
        const int row0 = (b2 >> 1) * 16;
        const int c0 = (b2 & 1) * 128 + wv * 32;
        short8 af[16];
#pragma unroll
        for (int i = 0; i < 16; ++i) {
            const float* src = (i < 8)
                ? (S_QP + (size_t)(row0 + lm) * 256 + i * 32 + quad * 8)
                : (S_SM + (size_t)(row0 + lm) * 256 + (i - 8) * 32 + quad * 8);
            float4 f0 = *(const float4*)src;
            float4 f1 = *(const float4*)(src + 4);
            short8 t;
            t[0] = (short)bf16r(f0.x); t[1] = (short)bf16r(f0.y);
            t[2] = (short)bf16r(f0.z); t[3] = (short)bf16r(f0.w);
            t[4] = (short)bf16r(f1.x); t[5] = (short)bf16r(f1.y);
            t[6] = (short)bf16r(f1.z); t[7] = (short)bf16r(f1.w);
            af[i] = t;
        }
#pragma unroll
        for (int j = 0; j < 2; ++j) {
            int n = c0 + j * 16 + lm;
            float bv = phiQb1[n];
            f32x4 acc = {bv, bv, bv, bv};
            const u16* wp = phiQ1T + (size_t)n * 512 + quad * 8;
#pragma unroll
            for (int i = 0; i < 16; ++i) {
                short8 bf = *(const short8*)(wp + i * 32);
                acc = __builtin_amdgcn_mfma_f32_16x16x32_bf16(af[i], bf, acc, 0, 0, 0);
            }
#pragma unroll
            for (int r = 0; r < 4; ++r) {
                int row = row0 + quad * 4 + r;
                Qmid[(size_t)row * 256 + n] = bf16r(fmaxf(acc[r], 0.f));
            }
        }
    }
}

// ======== K3: proj. [0,512) fused qp+K+V (A gathered from f_q), [512,640) q-proj
__global__ __launch_bounds__(256) void k3_proj(
    const float* __restrict__ f_q, const u16* __restrict__ Wqp,
    const u16* __restrict__ Wk, const u16* __restrict__ Wv,
    const float* __restrict__ sb, const float* __restrict__ qpW2,
    const float* __restrict__ qpb2, const float* __restrict__ P,
    const float* __restrict__ bk, const float* __restrict__ bv,
    float* __restrict__ outPhat, float* __restrict__ outV,
    float* __restrict__ Vw2, u16* __restrict__ kmb, u16* __restrict__ vtb,
    const u16* __restrict__ Qmid, const u16* __restrict__ Wf1T,
    const float* __restrict__ bf1, float qscale, u16* __restrict__ qmb) {
    __shared__ float red[4][16][2];
    int bid = blockIdx.x;
    const int wv = threadIdx.x >> 6, lane = threadIdx.x & 63;
    const int lm = lane & 15, quad = lane >> 4;
    if (bid >= 512) {
        mgemm_dev<3>(bid - 512, Qmid, Wf1T, bf1, qscale, qmb);
        return;
    }
    const int row0 = bid * 16;
    const int b = row0 >> 12;
    const int l = (row0 & 4095) + lm;
    const float* fb = f_q + (size_t)b * 256 * HW + l;
    short8 af[8];
#pragma unroll
    for (int i = 0; i < 8; ++i) {
        short8 t;
#pragma unroll
        for (int j = 0; j < 8; ++j)
            t[j] = (short)bf16r(fb[(size_t)(i * 32 + quad * 8 + j) * HW]);
        af[i] = t;
    }
    // --- qp part
    float c0p[4] = {0.f, 0.f, 0.f, 0.f}, c1p[4] = {0.f, 0.f, 0.f, 0.f};
#pragma unroll
    for (int j = 0; j < 4; ++j) {
        int n = wv * 64 + j * 16 + lm;
        float bv2 = sb[b * 256 + n];
        f32x4 acc = {bv2, bv2, bv2, bv2};
        const u16* wp = Wqp + (size_t)n * 256 + quad * 8;
#pragma unroll
        for (int i = 0; i < 8; ++i) {
            short8 bf = *(const short8*)(wp + i * 32);
            acc = __builtin_amdgcn_mfma_f32_16x16x32_bf16(af[i], bf, acc, 0, 0, 0);
        }
        float w20 = qpW2[n * 2], w21 = qpW2[n * 2 + 1];
#pragma unroll
        for (int r = 0; r < 4; ++r) {
            float hh = fmaxf(acc[r], 0.f);
            c0p[r] += hh * w20;
            c1p[r] += hh * w21;
        }
    }
#pragma unroll
    for (int m = 1; m < 16; m <<= 1) {
#pragma unroll
        for (int r = 0; r < 4; ++r) {
            c0p[r] += __shfl_xor(c0p[r], m);
            c1p[r] += __shfl_xor(c1p[r], m);
        }
    }
    if (lm == 0) {
#pragma unroll
        for (int r = 0; r < 4; ++r) {
            red[wv][quad * 4 + r][0] = c0p[r];
            red[wv][quad * 4 + r][1] = c1p[r];
        }
    }
    __syncthreads();
    int t = threadIdx.x;
    if (t < 16) {
        float ph0 = red[0][t][0] + red[1][t][0] + red[2][t][0] + red[3][t][0] + qpb2[0];
        float ph1 = red[0][t][1] + red[1][t][1] + red[2][t][1] + red[3][t][1] + qpb2[1];
        int hw = (row0 + t) & 4095;
        float Vv = ent2(ph0, ph1) -
                   ent2(P[(size_t)b * 8192 + hw], P[(size_t)b * 8192 + 4096 + hw]);
        outPhat[(size_t)b * 8192 + hw] = ph0;
        outPhat[(size_t)b * 8192 + 4096 + hw] = ph1;
        outV[b * 4096 + hw] = Vv;
        Vw2[b * 4096 + hw] = Vv * LOG2E;
    }
    // --- K part
#pragma unroll
    for (int j = 0; j < 4; ++j) {
        int n = wv * 64 + j * 16 + lm;
        float bv2 = bk[n];
        f32x4 acc = {bv2, bv2, bv2, bv2};
        const u16* wp = Wk + (size_t)n * 256 + quad * 8;
#pragma unroll
        for (int i = 0; i < 8; ++i) {
            short8 bf = *(const short8*)(wp + i * 32);
            acc = __builtin_amdgcn_mfma_f32_16x16x32_bf16(af[i], bf, acc, 0, 0, 0);
        }
#pragma unroll
        for (int r = 0; r < 4; ++r)
            kmb[(size_t)(row0 + quad * 4 + r) * 256 + n] = bf16r(acc[r]);
    }
    // --- V part (permuted head-transposed store)
#pragma unroll
    for (int j = 0; j < 4; ++j) {
        int n = wv * 64 + j * 16 + lm;
        float bv2 = bv[n];
        f32x4 acc = {bv2, bv2, bv2, bv2};
        const u16* wp = Wv + (size_t)n * 256 + quad * 8;
#pragma unroll
        for (int i = 0; i < 8; ++i) {
            short8 bf = *(const short8*)(wp + i * 32);
            acc = __builtin_amdgcn_mfma_f32_16x16x32_bf16(af[i], bf, acc, 0, 0, 0);
        }
#pragma unroll
        for (int r = 0; r < 4; ++r) {
            int row = row0 + quad * 4 + r;
            int l2 = row & 4095;
            int pos = (l2 & ~63) + ((l2 & 15) << 2) + ((l2 >> 4) & 3);
            vtb[((size_t)((b * 8 + (n >> 5)) * 32 + (n & 31))) * HW + pos] =
                bf16r(acc[r]);
        }
    }
}

// ======== K4: MFMA flash attention. 32 q/wave (2 q-frags), kv-split x8,
// LDS-staged K/V (triple buffer), no online max, linear combine downstream.
__global__ __launch_bounds__(256) void attn_mfma(const u16* __restrict__ qm,
                                                 const u16* __restrict__ km,
                                                 const u16* __restrict__ vt,
                                                 const float* __restrict__ vb2,
                                                 u16* __restrict__ Op,
                                                 float* __restrict__ Lp) {
    __shared__ __align__(16) u16 Kst[3][2048];
    __shared__ __align__(16) u16 Vst[3][2048];
    __shared__ __align__(16) u16 p_s[4][32][80];
    const int blk = blockIdx.x;   // 1024 = 2 b * 8 qt * 8 sp * 8 h
    const int h = blk & 7, sp = (blk >> 3) & 7, qt = (blk >> 6) & 7, b = blk >> 9;
    const int tid = threadIdx.x;
    const int wv = tid >> 6, lane = tid & 63;
    const int lm = lane & 15, quad = lane >> 4;
    const int q0 = qt * 128 + wv * 32;
    short8 qf[2];
#pragma unroll
    for (int s = 0; s < 2; ++s)
        qf[s] = *(const short8*)(qm + ((size_t)(b * LQ + q0 + s * 16 + lm)) * 256 +
                                 h * 32 + quad * 8);
    const u16* kbh = km + (size_t)b * HW * 256 + h * 32;
    const u16* vbh = vt + (size_t)(b * 8 + h) * 32 * HW;
    const float* vbb = vb2 + b * HW;
    const int krow = tid >> 2, kseg = tid & 3;
    const int vd = tid >> 3, vp = tid & 7, vs = (vp - vd) & 7;
    const int kv_lo = sp * 512;
    const short os = (short)0x3F80;  // bf16 1.0
    const short8 ones = {os, os, os, os, os, os, os, os};
    const f32x4 z4 = {0.f, 0.f, 0.f, 0.f};
    f32x4 o[2][2] = {{z4, z4}, {z4, z4}};
    f32x4 lr[2] = {z4, z4};
    glds16(kbh + (size_t)(kv_lo + krow) * 256 + kseg * 8, &Kst[0][wv * 512]);
    glds16(vbh + (size_t)vd * HW + kv_lo + vs * 8, &Vst[0][wv * 512]);
    glds16(kbh + (size_t)(kv_lo + 64 + krow) * 256 + kseg * 8, &Kst[1][wv * 512]);
    glds16(vbh + (size_t)vd * HW + kv_lo + 64 + vs * 8, &Vst[1][wv * 512]);
    for (int c = 0; c < 8; ++c) {
        __syncthreads();
        if (c + 2 < 8) {
            int kc2 = kv_lo + (c + 2) * 64, ib = (c + 2) % 3;
            glds16(kbh + (size_t)(kc2 + krow) * 256 + kseg * 8, &Kst[ib][wv * 512]);
            glds16(vbh + (size_t)vd * HW + kc2 + vs * 8, &Vst[ib][wv * 512]);
        }
        const int idx = c % 3;
        const int kc = kv_lo + c * 64;
        const u16* kbuf = Kst[idx];
        const u16* vbuf = Vst[idx];
        f32x4 st[2][4];
        float vbf[4];
#pragma unroll
        for (int t = 0; t < 4; ++t) {
            short8 kf = *(const short8*)(kbuf + (t * 16 + lm) * 32 + quad * 8);
            st[0][t] = __builtin_amdgcn_mfma_f32_16x16x32_bf16(qf[0], kf, z4, 0, 0, 0);
            st[1][t] = __builtin_amdgcn_mfma_f32_16x16x32_bf16(qf[1], kf, z4, 0, 0, 0);
            vbf[t] = vbb[kc + t * 16 + lm];
        }
#pragma unroll
        for (int s = 0; s < 2; ++s)
#pragma unroll
            for (int r = 0; r < 4; ++r) {
                float p0 = __builtin_amdgcn_exp2f(st[s][0][r] + vbf[0]);
                float p1 = __builtin_amdgcn_exp2f(st[s][1][r] + vbf[1]);
                float p2 = __builtin_amdgcn_exp2f(st[s][2][r] + vbf[2]);
                float p3 = __builtin_amdgcn_exp2f(st[s][3][r] + vbf[3]);
                ushort4 pk = {(u16)(__float_as_uint(p0) >> 16),
                              (u16)(__float_as_uint(p1) >> 16),
                              (u16)(__float_as_uint(p2) >> 16),
                              (u16)(__float_as_uint(p3) >> 16)};
                *(ushort4*)&p_s[wv][s * 16 + quad * 4 + r][lm * 4] = pk;
            }
        // p_s is wave-private; DS pipe in-order per wave -> no barrier needed.
#pragma unroll
        for (int hf = 0; hf < 2; ++hf) {
            int ss = (hf * 4 + quad + lm) & 7;
            short8 vf0 = *(const short8*)(vbuf + lm * 64 + ss * 8);
            short8 vf1 = *(const short8*)(vbuf + (16 + lm) * 64 + ss * 8);
#pragma unroll
            for (int s = 0; s < 2; ++s) {
                short8 pf = *(const short8*)&p_s[wv][s * 16 + lm][hf * 32 + quad * 8];
                lr[s] = __builtin_amdgcn_mfma_f32_16x16x32_bf16(pf, ones, lr[s], 0, 0, 0);
                o[s][0] = __builtin_amdgcn_mfma_f32_16x16x32_bf16(pf, vf0, o[s][0], 0, 0, 0);
                o[s][1] = __builtin_amdgcn_mfma_f32_16x16x32_bf16(pf, vf1, o[s][1], 0, 0, 0);
            }
        }
    }
#pragma unroll
    for (int s = 0; s < 2; ++s) {
        const int rowb = (b * 8 + h) * LQ + q0 + s * 16 + quad * 4;
#pragma unroll
        for (int r = 0; r < 4; ++r) {
            size_t ro = ((size_t)sp * 16384 + rowb + r) * 32;
            Op[ro + lm] = bf16r(o[s][0][r]);
            Op[ro + 16 + lm] = bf16r(o[s][1][r]);
            if (lm == 0) Lp[(size_t)sp * 16384 + rowb + r] = lr[s][r];
        }
    }
}

// ======== K56: fused linear split-combine + final GEMM.
__global__ __launch_bounds__(256) void k56_out(const u16* __restrict__ Op,
                                               const float* __restrict__ Lp,
                                               const u16* __restrict__ Wf2T,
                                               const float* __restrict__ bf2,
                                               const float* __restrict__ S_SM,
                                               float* __restrict__ outS) {
    __shared__ float uu[8][33];  // [h][rowIdx] = 1/sum_s L
    const int bid = blockIdx.x;
    const int row0 = (bid >> 2) * 32;       // over 2048 (b,q) rows
    const int n0 = (bid & 3) * 64;
    const int t = threadIdx.x;
    {
        int i = t >> 3, h = t & 7;
        int grow = row0 + i;
        int b = grow >> 10, q = grow & 1023;
        int r2 = (b * 8 + h) * 1024 + q;
        float LS = 0.f;
#pragma unroll
        for (int s = 0; s < 8; ++s) LS += Lp[s * 16384 + r2];
        uu[h][i] = 1.f / LS;
    }
    __syncthreads();
    const int wv = t >> 6, lane = t & 63;
    const int lm = lane & 15, quad = lane >> 4;
    const int s2 = wv >> 1, jc = wv & 1;
    const int rI = s2 * 16 + lm;
    const int grow = row0 + rI;
    const int b = grow >> 10, q = grow & 1023;
    short8 af[8];
#pragma unroll
    for (int i = 0; i < 8; ++i) {  // head i, d = quad*8..+8
        float a[8] = {0.f, 0.f, 0.f, 0.f, 0.f, 0.f, 0.f, 0.f};
        const u16* ob = Op + ((size_t)(b * 8 + i) * 1024 + q) * 32 + quad * 8;
#pragma unroll
        for (int sp = 0; sp < 8; ++sp) {
            short8 ov = *(const short8*)(ob + (size_t)sp * 16384 * 32);
#pragma unroll
            for (int j = 0; j < 8; ++j) a[j] += b2f((u16)ov[j]);
        }
        float il = uu[i][rI];
        short8 pk;
#pragma unroll
        for (int j = 0; j < 8; ++j) pk[j] = (short)bf16r(a[j] * il);
        af[i] = pk;
    }
    f32x4 acc[2];
#pragma unroll
    for (int j = 0; j < 2; ++j) {
        int n = n0 + jc * 32 + j * 16 + lm;
        float bv = bf2[n];
        acc[j] = f32x4{bv, bv, bv, bv};
        const u16* wp = Wf2T + (size_t)n * 256 + quad * 8;
#pragma unroll
        for (int i = 0; i < 8; ++i) {
            short8 bf = *(const short8*)(wp + i * 32);
            acc[j] = __builtin_amdgcn_mfma_f32_16x16x32_bf16(af[i], bf, acc[j], 0, 0, 0);
        }
    }
#pragma unroll
    for (int j = 0; j < 2; ++j) {
        int n = n0 + jc * 32 + j * 16 + lm;
#pragma unroll
        for (int r = 0; r < 4; ++r) {
            int row = row0 + s2 * 16 + quad * 4 + r;
            outS[(size_t)row * 256 + n] = S_SM[(size_t)row * 256 + n] - acc[j][r];
        }
    }
}

extern "C" void kernel_launch(void* const* d_in, const int* in_sizes, int n_in,
                              void* d_out, int out_size, void* d_ws, size_t ws_size,
                              hipStream_t stream) {
    const float* S_QP = (const float*)d_in[0];
    const float* S_SM = (const float*)d_in[1];
    const float* f_q = (const float*)d_in[2];
    const float* P = (const float*)d_in[3];
    const float* qp_W1 = (const float*)d_in[4];
    const float* qp_b1 = (const float*)d_in[5];
    const float* qp_W2 = (const float*)d_in[6];
    const float* qp_b2 = (const float*)d_in[7];
    const float* phiQ_W1 = (const float*)d_in[8];
    const float* phiQ_b1 = (const float*)d_in[9];
    const float* phiQ_W2 = (const float*)d_in[10];
    const float* phiQ_b2 = (const float*)d_in[11];
    const float* Wq = (const float*)d_in[12];
    const float* bq = (const float*)d_in[13];
    const float* Wk = (const float*)d_in[14];
    const float* bk = (const float*)d_in[15];
    const float* Wv = (const float*)d_in[16];
    const float* bv = (const float*)d_in[17];
    const float* Wo = (const float*)d_in[18];
    const float* bo = (const float*)d_in[19];
    const float* phi_W = (const float*)d_in[20];
    const float* phi_b = (const float*)d_in[21];

    float* out = (float*)d_out;
    float* outS = out;            // [2,1024,256]
    float* outP = out + 524288;   // [2,2,64,64]
    float* outV = out + 540672;   // [2,1,64,64]

    float* spart = (float*)d_ws;           // 8192 (32x256 mean partials)
    float* sb = spart + 8192;              // 512
    float* Vw2 = sb + 512;                 // 8192
    float* Lp = Vw2 + 8192;                // 131072
    float* bf1 = Lp + 131072;              // 256
    float* bf2 = bf1 + 256;                // 256
    u16* qpW1loT = (u16*)(bf2 + 256);      // 65536
    u16* WkT = qpW1loT + 65536;
    u16* WvT = WkT + 65536;
    u16* phiQ1T = WvT + 65536;             // 131072 (256x512)
    u16* WqT = phiQ1T + 131072;
    u16* phiWT = WqT + 65536;
    u16* phiQ2s = phiWT + 65536;
    u16* Wos = phiQ2s + 65536;
    u16* Wf1T = Wos + 65536;
    u16* Wf2T = Wf1T + 65536;
    u16* Qmid = Wf2T + 65536;              // 524288
    u16* qmb = Qmid + 524288;              // 524288
    u16* kmb = qmb + 524288;               // 2097152
    u16* vtb = kmb + 2097152;              // 2097152
    u16* Op16 = vtb + 2097152;             // 4194304

    const float qscale = 0.17677669529663687f * LOG2E;

    k1_prep<<<610, 256, 0, stream>>>(qp_W1 + 65536, Wk, Wv, phiQ_W1, Wq, phi_W,
                                     phiQ_W2, Wo, qpW1loT, WkT, WvT, phiQ1T, WqT,
                                     phiWT, phiQ2s, Wos, phiQ_b2, bq, bo, phi_b,
                                     bf1, bf2, S_SM, spart);
    k2_mid<<<290, 256, 0, stream>>>(spart, qp_W1, qp_b1, sb, WqT, phiQ2s, Wf1T,
                                    phiWT, Wos, Wf2T, S_QP, S_SM, phiQ1T,
                                    phiQ_b1, Qmid);
    k3_proj<<<640, 256, 0, stream>>>(f_q, qpW1loT, WkT, WvT, sb, qp_W2, qp_b2, P,
                                     bk, bv, outP, outV, Vw2, kmb, vtb, Qmid, Wf1T,
                                     bf1, qscale, qmb);
    attn_mfma<<<1024, 256, 0, stream>>>(qmb, kmb, vtb, Vw2, Op16, Lp);
    k56_out<<<256, 256, 0, stream>>>(Op16, Lp, Wf2T, bf2, S_SM, outS);
}

// Round 9
// 183.577 us; speedup vs baseline: 1.0180x; 1.0180x over previous
//
#include <hip/hip_runtime.h>
#include <math.h>

// B=2, Lq=1024, C=256, H=W=64 -> Lk=4096, NC=2, NH=8, D=32.
// R9: attention computes S^T = mfma(K,Q) so P^T's C-regs ARE a valid PV
// B-fragment (V stored kv-permuted p(16t+4q+r)=8q+4t+r) -> no P LDS
// round-trip. V-bias folded into V and L via e=exp(V) (k3 pre-scales V,
// emits e array). O^T accumulated in C-layout; DS/chunk halved, LDS 12.5KB.
// k56: combine reads Op once into padded LDS, GEMM from LDS.

#define LQ 1024
#define HW 4096
#define LOG2E 1.4426950408889634f

typedef __attribute__((ext_vector_type(8))) short short8;
typedef __attribute__((ext_vector_type(4))) float f32x4;
typedef unsigned short u16;

__device__ __forceinline__ u16 bf16r(float x) {
    unsigned int u = __float_as_uint(x);
    u = (u + 0x7FFFu + ((u >> 16) & 1u)) >> 16;
    return (u16)u;
}

__device__ __forceinline__ float b2f(u16 v) {
    return __uint_as_float((unsigned)v << 16);
}

__device__ __forceinline__ float ent2(float a, float b) {
    float m  = fmaxf(a, b);
    float e0 = expf(a - m), e1 = expf(b - m);
    float iz = 1.f / (e0 + e1);
    float p0 = fmaxf(e0 * iz, 1e-8f);
    float p1 = fmaxf(e1 * iz, 1e-8f);
    return -(p0 * logf(p0) + p1 * logf(p1));
}

typedef __attribute__((address_space(1))) const unsigned int gas_u32;
typedef __attribute__((address_space(3))) unsigned int las_u32;
__device__ __forceinline__ void glds16(const void* g, void* l) {
    __builtin_amdgcn_global_load_lds((gas_u32*)g, (las_u32*)l, 16, 0, 0);
}

// kv-permutation within a 32-group: p(16t + 4q2 + r) = 8*q2 + 4*t + r
__device__ __forceinline__ int kvperm(int l) {
    int w = l & 31;
    return (l & ~31) | (((w >> 2) & 3) << 3) | (((w >> 4) & 1) << 2) | (w & 3);
}

// ---- device MFMA GEMM core: 32 rows x 128 cols per bid-pair (4 waves).
template <int EPI>
__device__ __forceinline__ void mgemm_dev(int bid, const u16* __restrict__ A,
                                          const u16* __restrict__ Wt,
                                          const float* __restrict__ bias,
                                          float scale, u16* __restrict__ out16) {
    const int wv = threadIdx.x >> 6, lane = threadIdx.x & 63;
    const int lm = lane & 15, quad = lane >> 4;
    const int row0 = (bid >> 1) * 32;
    const int c0 = (bid & 1) * 128 + wv * 32;
    short8 af[2][8];
#pragma unroll
    for (int s = 0; s < 2; ++s)
#pragma unroll
        for (int i = 0; i < 8; ++i)
            af[s][i] = *(const short8*)(A + (size_t)(row0 + s * 16 + lm) * 256 +
                                        i * 32 + quad * 8);
    f32x4 acc[2][2];
#pragma unroll
    for (int j = 0; j < 2; ++j) {
        float bv = bias ? bias[c0 + j * 16 + lm] : 0.f;
        acc[0][j] = f32x4{bv, bv, bv, bv};
        acc[1][j] = acc[0][j];
    }
#pragma unroll
    for (int j = 0; j < 2; ++j) {
        const u16* wp = Wt + (size_t)(c0 + j * 16 + lm) * 256 + quad * 8;
#pragma unroll
        for (int i = 0; i < 8; ++i) {
            short8 bf = *(const short8*)(wp + i * 32);
#pragma unroll
            for (int s = 0; s < 2; ++s)
                acc[s][j] = __builtin_amdgcn_mfma_f32_16x16x32_bf16(af[s][i], bf,
                                                                    acc[s][j], 0, 0, 0);
        }
    }
#pragma unroll
    for (int s = 0; s < 2; ++s)
#pragma unroll
        for (int j = 0; j < 2; ++j) {
            int n = c0 + j * 16 + lm;
#pragma unroll
            for (int r = 0; r < 4; ++r) {
                int row = row0 + s * 16 + quad * 4 + r;
                float v = acc[s][j][r];
                if (EPI == 3) v *= scale;
                out16[(size_t)row * 256 + n] = bf16r(v);
            }
        }
}

// ======== K1: prep. [0,576) weights, [576,578) bias_fuse, [578,610) mean partials
__global__ __launch_bounds__(256) void k1_prep(
    const float* qpW1hi, const float* Wk, const float* Wv, const float* phiQ1,
    const float* Wq, const float* phiW, const float* phiQ2, const float* Wo,
    u16* qpW1loT, u16* WkT, u16* WvT, u16* phiQ1T, u16* WqT, u16* phiWT,
    u16* phiQ2s, u16* Wos,
    const float* pb2, const float* bq, const float* bo, const float* phib,
    float* bf1, float* bf2,
    const float* S_SM, float* spart) {
    __shared__ float tile[32][33];
    int bid = blockIdx.x;
    if (bid < 576) {
        if (bid >= 448) {
            int b2 = bid - 448;
            const float* S = (b2 < 64) ? phiQ2 : Wo;
            u16* D = (b2 < 64) ? phiQ2s : Wos;
            int idx = ((b2 & 63) * 256 + threadIdx.x) * 4;
            float4 v = *(const float4*)&S[idx];
            ushort4 pk = {bf16r(v.x), bf16r(v.y), bf16r(v.z), bf16r(v.w)};
            *(ushort4*)&D[idx] = pk;
            return;
        }
        const float* S; u16* D; int K;
        if (bid < 64)       { S = qpW1hi; D = qpW1loT; K = 256; }
        else if (bid < 128) { S = Wk; D = WkT; K = 256; bid -= 64; }
        else if (bid < 192) { S = Wv; D = WvT; K = 256; bid -= 128; }
        else if (bid < 320) { S = phiQ1; D = phiQ1T; K = 512; bid -= 192; }
        else if (bid < 384) { S = Wq; D = WqT; K = 256; bid -= 320; }
        else                { S = phiW; D = phiWT; K = 256; bid -= 384; }
        int KT = K >> 5;
        int tk = bid % KT, tn = bid / KT;
        int cc = threadIdx.x & 31, rb = threadIdx.x >> 5;
#pragma unroll
        for (int i = 0; i < 4; ++i) {
            int rr = rb + i * 8;
            tile[rr][cc] = S[(size_t)(tk * 32 + rr) * 256 + tn * 32 + cc];
        }
        __syncthreads();
#pragma unroll
        for (int i = 0; i < 4; ++i) {
            int rr = rb + i * 8;
            D[(size_t)(tn * 32 + rr) * K + tk * 32 + cc] = bf16r(tile[cc][rr]);
        }
    } else if (bid < 578) {
        int n = threadIdx.x;
        if (bid == 576) {
            float a = bq[n];
            for (int c = 0; c < 256; ++c) a += pb2[c] * Wq[c * 256 + n];
            bf1[n] = a;
        } else {
            float a = phib[n];
            for (int c = 0; c < 256; ++c) a += bo[c] * phiW[c * 256 + n];
            bf2[n] = a;
        }
    } else {
        int bi = bid - 578;
        int b = bi >> 4, l0 = (bi & 15) * 64;
        int c = threadIdx.x;
        const float* p = S_SM + (size_t)b * LQ * 256 + (size_t)l0 * 256 + c;
        float acc = 0.f;
#pragma unroll 8
        for (int l = 0; l < 64; ++l) acc += p[(size_t)l * 256];
        spart[bi * 256 + c] = acc;
    }
}

// ======== K2: mid. [0,2) sbias, [2,18) Wf1T, [18,34) Wf2T, [34,290) phiQ1
__global__ __launch_bounds__(256) void k2_mid(
    const float* spart, const float* qpW1, const float* qpb1, float* sb,
    const u16* WqT, const u16* phiQ2s, u16* Wf1T,
    const u16* phiWT, const u16* Wos, u16* Wf2T,
    const float* S_QP, const float* S_SM, const u16* phiQ1T,
    const float* phiQb1, u16* Qmid) {
    __shared__ float s_s[256];
    int bid = blockIdx.x;
    if (bid < 2) {
        int b = bid, o = threadIdx.x;
        float sm = 0.f;
#pragma unroll
        for (int p = 0; p < 16; ++p) sm += spart[(b * 16 + p) * 256 + o];
        s_s[o] = sm * (1.f / 1024.f);
        __syncthreads();
        float acc = qpb1[o];
        for (int c = 0; c < 256; ++c) acc += s_s[c] * qpW1[c * 256 + o];
        sb[b * 256 + o] = acc;
    } else if (bid < 18) {
        mgemm_dev<0>(bid - 2, WqT, phiQ2s, nullptr, 0.f, Wf1T);
    } else if (bid < 34) {
        mgemm_dev<0>(bid - 18, phiWT, Wos, nullptr, 0.f, Wf2T);
    } else {
        int b2 = bid - 34;
        const int wv = threadIdx.x >> 6, lane = threadIdx.x & 63;
        const int lm = lane & 15, quad = lane >> 4;
        const int row0 = (b2 >> 1) * 16;
        const int c0 = (b2 & 1) * 128 + wv * 32;
        short8 af[16];
#pragma unroll
        for (int i = 0; i < 16; ++i) {
            const float* src = (i < 8)
                ? (S_QP + (size_t)(row0 + lm) * 256 + i * 32 + quad * 8)
                : (S_SM + (size_t)(row0 + lm) * 256 + (i - 8) * 32 + quad * 8);
            float4 f0 = *(const float4*)src;
            float4 f1 = *(const float4*)(src + 4);
            short8 t;
            t[0] = (short)bf16r(f0.x); t[1] = (short)bf16r(f0.y);
            t[2] = (short)bf16r(f0.z); t[3] = (short)bf16r(f0.w);
            t[4] = (short)bf16r(f1.x); t[5] = (short)bf16r(f1.y);
            t[6] = (short)bf16r(f1.z); t[7] = (short)bf16r(f1.w);
            af[i] = t;
        }
#pragma unroll
        for (int j = 0; j < 2; ++j) {
            int n = c0 + j * 16 + lm;
            float bv = phiQb1[n];
            f32x4 acc = {bv, bv, bv, bv};
            const u16* wp = phiQ1T + (size_t)n * 512 + quad * 8;
#pragma unroll
            for (int i = 0; i < 16; ++i) {
                short8 bf = *(const short8*)(wp + i * 32);
                acc = __builtin_amdgcn_mfma_f32_16x16x32_bf16(af[i], bf, acc, 0, 0, 0);
            }
#pragma unroll
            for (int r = 0; r < 4; ++r) {
                int row = row0 + quad * 4 + r;
                Qmid[(size_t)row * 256 + n] = bf16r(fmaxf(acc[r], 0.f));
            }
        }
    }
}

// ======== K3: proj. [0,512) fused qp+K+V (A from f_q), [512,640) q-proj.
// V rows pre-scaled by e=exp(V-bias); e emitted (bf16, kv-permuted).
__global__ __launch_bounds__(256) void k3_proj(
    const float* __restrict__ f_q, const u16* __restrict__ Wqp,
    const u16* __restrict__ Wk, const u16* __restrict__ Wv,
    const float* __restrict__ sb, const float* __restrict__ qpW2,
    const float* __restrict__ qpb2, const float* __restrict__ P,
    const float* __restrict__ bk, const float* __restrict__ bv,
    float* __restrict__ outPhat, float* __restrict__ outV,
    u16* __restrict__ evb, u16* __restrict__ kmb, u16* __restrict__ vtb,
    const u16* __restrict__ Qmid, const u16* __restrict__ Wf1T,
    const float* __restrict__ bf1, float qscale, u16* __restrict__ qmb) {
    __shared__ float red[4][16][2];
    __shared__ float evl[16];
    int bid = blockIdx.x;
    const int wv = threadIdx.x >> 6, lane = threadIdx.x & 63;
    const int lm = lane & 15, quad = lane >> 4;
    if (bid >= 512) {
        mgemm_dev<3>(bid - 512, Qmid, Wf1T, bf1, qscale, qmb);
        return;
    }
    const int row0 = bid * 16;
    const int b = row0 >> 12;
    const int l = (row0 & 4095) + lm;
    const float* fb = f_q + (size_t)b * 256 * HW + l;
    short8 af[8];
#pragma unroll
    for (int i = 0; i < 8; ++i) {
        short8 t;
#pragma unroll
        for (int j = 0; j < 8; ++j)
            t[j] = (short)bf16r(fb[(size_t)(i * 32 + quad * 8 + j) * HW]);
        af[i] = t;
    }
    // --- qp part
    float c0p[4] = {0.f, 0.f, 0.f, 0.f}, c1p[4] = {0.f, 0.f, 0.f, 0.f};
#pragma unroll
    for (int j = 0; j < 4; ++j) {
        int n = wv * 64 + j * 16 + lm;
        float bv2 = sb[b * 256 + n];
        f32x4 acc = {bv2, bv2, bv2, bv2};
        const u16* wp = Wqp + (size_t)n * 256 + quad * 8;
#pragma unroll
        for (int i = 0; i < 8; ++i) {
            short8 bf = *(const short8*)(wp + i * 32);
            acc = __builtin_amdgcn_mfma_f32_16x16x32_bf16(af[i], bf, acc, 0, 0, 0);
        }
        float w20 = qpW2[n * 2], w21 = qpW2[n * 2 + 1];
#pragma unroll
        for (int r = 0; r < 4; ++r) {
            float hh = fmaxf(acc[r], 0.f);
            c0p[r] += hh * w20;
            c1p[r] += hh * w21;
        }
    }
#pragma unroll
    for (int m = 1; m < 16; m <<= 1) {
#pragma unroll
        for (int r = 0; r < 4; ++r) {
            c0p[r] += __shfl_xor(c0p[r], m);
            c1p[r] += __shfl_xor(c1p[r], m);
        }
    }
    if (lm == 0) {
#pragma unroll
        for (int r = 0; r < 4; ++r) {
            red[wv][quad * 4 + r][0] = c0p[r];
            red[wv][quad * 4 + r][1] = c1p[r];
        }
    }
    __syncthreads();
    int t = threadIdx.x;
    if (t < 16) {
        float ph0 = red[0][t][0] + red[1][t][0] + red[2][t][0] + red[3][t][0] + qpb2[0];
        float ph1 = red[0][t][1] + red[1][t][1] + red[2][t][1] + red[3][t][1] + qpb2[1];
        int lg = row0 + t;
        int hw = lg & 4095;
        float Vv = ent2(ph0, ph1) -
                   ent2(P[(size_t)b * 8192 + hw], P[(size_t)b * 8192 + 4096 + hw]);
        outPhat[(size_t)b * 8192 + hw] = ph0;
        outPhat[(size_t)b * 8192 + 4096 + hw] = ph1;
        outV[b * 4096 + hw] = Vv;
        float ev = expf(Vv);
        evl[t] = ev;
        evb[b * HW + kvperm(hw)] = bf16r(ev);
    }
    // --- K part
#pragma unroll
    for (int j = 0; j < 4; ++j) {
        int n = wv * 64 + j * 16 + lm;
        float bv2 = bk[n];
        f32x4 acc = {bv2, bv2, bv2, bv2};
        const u16* wp = Wk + (size_t)n * 256 + quad * 8;
#pragma unroll
        for (int i = 0; i < 8; ++i) {
            short8 bf = *(const short8*)(wp + i * 32);
            acc = __builtin_amdgcn_mfma_f32_16x16x32_bf16(af[i], bf, acc, 0, 0, 0);
        }
#pragma unroll
        for (int r = 0; r < 4; ++r)
            kmb[(size_t)(row0 + quad * 4 + r) * 256 + n] = bf16r(acc[r]);
    }
    __syncthreads();  // evl visible to all
    // --- V part: scale rows by e, store [b,h,d][kv'] with kvperm
#pragma unroll
    for (int j = 0; j < 4; ++j) {
        int n = wv * 64 + j * 16 + lm;
        float bv2 = bv[n];
        f32x4 acc = {bv2, bv2, bv2, bv2};
        const u16* wp = Wv + (size_t)n * 256 + quad * 8;
#pragma unroll
        for (int i = 0; i < 8; ++i) {
            short8 bf = *(const short8*)(wp + i * 32);
            acc = __builtin_amdgcn_mfma_f32_16x16x32_bf16(af[i], bf, acc, 0, 0, 0);
        }
#pragma unroll
        for (int r = 0; r < 4; ++r) {
            int row = row0 + quad * 4 + r;
            int l2 = row & 4095;
            int pos = kvperm(l2);
            float vvv = acc[r] * evl[quad * 4 + r];
            vtb[((size_t)((b * 8 + (n >> 5)) * 32 + (n & 31))) * HW + pos] = bf16r(vvv);
        }
    }
}

// ======== K4: MFMA flash attention, transpose-free.
// S^T = mfma(K-frag, Q-frag); P^T C-regs feed PV directly as B-frags
// (V kv-permuted); O^T accumulated; L via e-frag MFMA. kv-split x8.
__global__ __launch_bounds__(256) void attn_mfma(const u16* __restrict__ qm,
                                                 const u16* __restrict__ km,
                                                 const u16* __restrict__ vt,
                                                 const u16* __restrict__ evb,
                                                 u16* __restrict__ Op,
                                                 float* __restrict__ Lp) {
    __shared__ __align__(16) u16 Kst[3][2048];   // [kv 64][d 32]
    __shared__ __align__(16) u16 Vst[3][2048];   // [d 32][kv' 64] seg-rotated
    const int blk = blockIdx.x;   // 1024 = 2b * 8qt * 8sp * 8h
    const int h = blk & 7, sp = (blk >> 3) & 7, qt = (blk >> 6) & 7, b = blk >> 9;
    const int tid = threadIdx.x;
    const int wv = tid >> 6, lane = tid & 63;
    const int lm = lane & 15, quad = lane >> 4;
    const int q0 = qt * 128 + wv * 32;
    short8 qf[2];
#pragma unroll
    for (int s = 0; s < 2; ++s)
        qf[s] = *(const short8*)(qm + ((size_t)(b * LQ + q0 + s * 16 + lm)) * 256 +
                                 h * 32 + quad * 8);
    const u16* kbh = km + (size_t)b * HW * 256 + h * 32;
    const u16* vbh = vt + (size_t)(b * 8 + h) * 32 * HW;
    const u16* eb = evb + (size_t)b * HW;
    const int krow = tid >> 2, kseg = tid & 3;
    const int vd = tid >> 3, vp = tid & 7, vs = (vp - vd) & 7;
    const int kv_lo = sp * 512;
    const f32x4 z4 = {0.f, 0.f, 0.f, 0.f};
    f32x4 o[2][2] = {{z4, z4}, {z4, z4}};  // [qfrag][dtile], O^T C-layout
    f32x4 lr[2] = {z4, z4};
    glds16(kbh + (size_t)(kv_lo + krow) * 256 + kseg * 8, &Kst[0][wv * 512]);
    glds16(vbh + (size_t)vd * HW + kv_lo + vs * 8, &Vst[0][wv * 512]);
    glds16(kbh + (size_t)(kv_lo + 64 + krow) * 256 + kseg * 8, &Kst[1][wv * 512]);
    glds16(vbh + (size_t)vd * HW + kv_lo + 64 + vs * 8, &Vst[1][wv * 512]);
    const int vss = (quad + lm) & 7;  // base seg rotation for V reads (d=lm)
    for (int c = 0; c < 8; ++c) {
        __syncthreads();
        if (c + 2 < 8) {
            int kc2 = kv_lo + (c + 2) * 64, ib = (c + 2) % 3;
            glds16(kbh + (size_t)(kc2 + krow) * 256 + kseg * 8, &Kst[ib][wv * 512]);
            glds16(vbh + (size_t)vd * HW + kc2 + vs * 8, &Vst[ib][wv * 512]);
        }
        const int idx = c % 3;
        const int kc = kv_lo + c * 64;
        const u16* kbuf = Kst[idx];
        const u16* vbuf = Vst[idx];
        // S^T: 4 kv-tiles x 2 q-frags
        f32x4 st[2][4];
#pragma unroll
        for (int tt = 0; tt < 4; ++tt) {
            short8 kf = *(const short8*)(kbuf + (tt * 16 + lm) * 32 + quad * 8);
            st[0][tt] = __builtin_amdgcn_mfma_f32_16x16x32_bf16(kf, qf[0], z4, 0, 0, 0);
            st[1][tt] = __builtin_amdgcn_mfma_f32_16x16x32_bf16(kf, qf[1], z4, 0, 0, 0);
        }
        // exp2 + pack: P^T B-frags, reg j -> kv-tile (c2*2 + (j>>2)), r=j&3
        short8 pf[2][2];
#pragma unroll
        for (int s = 0; s < 2; ++s)
#pragma unroll
            for (int c2 = 0; c2 < 2; ++c2) {
                short8 pk;
#pragma unroll
                for (int j = 0; j < 8; ++j) {
                    float pv = __builtin_amdgcn_exp2f(st[s][c2 * 2 + (j >> 2)][j & 3]);
                    pk[j] = (short)(__float_as_uint(pv) >> 16);
                }
                pf[s][c2] = pk;
            }
#pragma unroll
        for (int c2 = 0; c2 < 2; ++c2) {
            short8 ef = *(const short8*)(eb + kc + c2 * 32 + quad * 8);
            short8 vf0 = *(const short8*)(vbuf + lm * 64 +
                                          ((c2 * 4 + vss) & 7) * 8);
            short8 vf1 = *(const short8*)(vbuf + (16 + lm) * 64 +
                                          ((c2 * 4 + vss) & 7) * 8);
#pragma unroll
            for (int s = 0; s < 2; ++s) {
                lr[s] = __builtin_amdgcn_mfma_f32_16x16x32_bf16(ef, pf[s][c2], lr[s], 0, 0, 0);
                o[s][0] = __builtin_amdgcn_mfma_f32_16x16x32_bf16(vf0, pf[s][c2], o[s][0], 0, 0, 0);
                o[s][1] = __builtin_amdgcn_mfma_f32_16x16x32_bf16(vf1, pf[s][c2], o[s][1], 0, 0, 0);
            }
        }
    }
    // store: O^T C-layout -> Op[row=q][d]; lane q = lane&15, d = dt*16+quad*4+r
#pragma unroll
    for (int s = 0; s < 2; ++s) {
        int qg = q0 + s * 16 + lm;
        size_t rbase = (size_t)sp * 16384 + (size_t)(b * 8 + h) * LQ + qg;
#pragma unroll
        for (int dt = 0; dt < 2; ++dt)
#pragma unroll
            for (int r = 0; r < 4; ++r)
                Op[rbase * 32 + dt * 16 + quad * 4 + r] = bf16r(o[s][dt][r]);
        if (quad == 0) Lp[rbase] = lr[s][0];
    }
}

// ======== K56: combine (Op read once, into padded LDS) + final GEMM.
// 128 blocks x 16 rows. out = S_SM - (sum O / sum L) @ Wf2 - bf2
__global__ __launch_bounds__(256) void k56_out(const u16* __restrict__ Op,
                                               const float* __restrict__ Lp,
                                               const u16* __restrict__ Wf2T,
                                               const float* __restrict__ bf2,
                                               const float* __restrict__ S_SM,
                                               float* __restrict__ outS) {
    __shared__ __align__(16) u16 comb[16][264];  // +8 pad -> conflict-free b128
    const int bid = blockIdx.x;
    const int row0 = bid * 16;
    const int t = threadIdx.x;
    {  // phase A: thread = (row, 16-ch group)
        int rowi = t >> 4, chg = (t & 15) * 16;
        int grow = row0 + rowi;
        int b = grow >> 10, q = grow & 1023;
        int hh = chg >> 5, d0 = chg & 31;
        const u16* ob = Op + ((size_t)(b * 8 + hh) * 1024 + q) * 32 + d0;
        float a[16];
#pragma unroll
        for (int j = 0; j < 16; ++j) a[j] = 0.f;
        float LS = 0.f;
#pragma unroll
        for (int s = 0; s < 8; ++s) {
            short8 v0 = *(const short8*)(ob + (size_t)s * 16384 * 32);
            short8 v1 = *(const short8*)(ob + (size_t)s * 16384 * 32 + 8);
#pragma unroll
            for (int j = 0; j < 8; ++j) {
                a[j] += b2f((u16)v0[j]);
                a[8 + j] += b2f((u16)v1[j]);
            }
            LS += Lp[(size_t)s * 16384 + (size_t)(b * 8 + hh) * 1024 + q];
        }
        float il = 1.f / LS;
#pragma unroll
        for (int g = 0; g < 4; ++g) {
            ushort4 pk = {bf16r(a[g * 4] * il), bf16r(a[g * 4 + 1] * il),
                          bf16r(a[g * 4 + 2] * il), bf16r(a[g * 4 + 3] * il)};
            *(ushort4*)&comb[rowi][chg + g * 4] = pk;
        }
    }
    __syncthreads();
    const int wv = t >> 6, lane = t & 63;
    const int lm = lane & 15, quad = lane >> 4;
    short8 af[8];
#pragma unroll
    for (int i = 0; i < 8; ++i)
        af[i] = *(const short8*)&comb[lm][i * 32 + quad * 8];
    f32x4 acc[4];
#pragma unroll
    for (int j = 0; j < 4; ++j) {
        int n = wv * 64 + j * 16 + lm;
        float bv = bf2[n];
        acc[j] = f32x4{bv, bv, bv, bv};
        const u16* wp = Wf2T + (size_t)n * 256 + quad * 8;
#pragma unroll
        for (int i = 0; i < 8; ++i) {
            short8 bf = *(const short8*)(wp + i * 32);
            acc[j] = __builtin_amdgcn_mfma_f32_16x16x32_bf16(af[i], bf, acc[j], 0, 0, 0);
        }
    }
#pragma unroll
    for (int j = 0; j < 4; ++j) {
        int n = wv * 64 + j * 16 + lm;
#pragma unroll
        for (int r = 0; r < 4; ++r) {
            int row = row0 + quad * 4 + r;
            outS[(size_t)row * 256 + n] = S_SM[(size_t)row * 256 + n] - acc[j][r];
        }
    }
}

extern "C" void kernel_launch(void* const* d_in, const int* in_sizes, int n_in,
                              void* d_out, int out_size, void* d_ws, size_t ws_size,
                              hipStream_t stream) {
    const float* S_QP = (const float*)d_in[0];
    const float* S_SM = (const float*)d_in[1];
    const float* f_q = (const float*)d_in[2];
    const float* P = (const float*)d_in[3];
    const float* qp_W1 = (const float*)d_in[4];
    const float* qp_b1 = (const float*)d_in[5];
    const float* qp_W2 = (const float*)d_in[6];
    const float* qp_b2 = (const float*)d_in[7];
    const float* phiQ_W1 = (const float*)d_in[8];
    const float* phiQ_b1 = (const float*)d_in[9];
    const float* phiQ_W2 = (const float*)d_in[10];
    const float* phiQ_b2 = (const float*)d_in[11];
    const float* Wq = (const float*)d_in[12];
    const float* bq = (const float*)d_in[13];
    const float* Wk = (const float*)d_in[14];
    const float* bk = (const float*)d_in[15];
    const float* Wv = (const float*)d_in[16];
    const float* bv = (const float*)d_in[17];
    const float* Wo = (const float*)d_in[18];
    const float* bo = (const float*)d_in[19];
    const float* phi_W = (const float*)d_in[20];
    const float* phi_b = (const float*)d_in[21];

    float* out = (float*)d_out;
    float* outS = out;            // [2,1024,256]
    float* outP = out + 524288;   // [2,2,64,64]
    float* outV = out + 540672;   // [2,1,64,64]

    float* spart = (float*)d_ws;           // 8192
    float* sb = spart + 8192;              // 512
    float* Lp = sb + 512;                  // 131072
    float* bf1 = Lp + 131072;              // 256
    float* bf2 = bf1 + 256;                // 256
    u16* qpW1loT = (u16*)(bf2 + 256);      // 65536
    u16* WkT = qpW1loT + 65536;
    u16* WvT = WkT + 65536;
    u16* phiQ1T = WvT + 65536;             // 131072 (256x512)
    u16* WqT = phiQ1T + 131072;
    u16* phiWT = WqT + 65536;
    u16* phiQ2s = phiWT + 65536;
    u16* Wos = phiQ2s + 65536;
    u16* Wf1T = Wos + 65536;
    u16* Wf2T = Wf1T + 65536;
    u16* evb = Wf2T + 65536;               // 8192 (bf16, kv-permuted)
    u16* Qmid = evb + 8192;                // 524288
    u16* qmb = Qmid + 524288;              // 524288
    u16* kmb = qmb + 524288;               // 2097152
    u16* vtb = kmb + 2097152;              // 2097152 (V^T * e, kv-permuted)
    u16* Op16 = vtb + 2097152;             // 4194304

    const float qscale = 0.17677669529663687f * LOG2E;

    k1_prep<<<610, 256, 0, stream>>>(qp_W1 + 65536, Wk, Wv, phiQ_W1, Wq, phi_W,
                                     phiQ_W2, Wo, qpW1loT, WkT, WvT, phiQ1T, WqT,
                                     phiWT, phiQ2s, Wos, phiQ_b2, bq, bo, phi_b,
                                     bf1, bf2, S_SM, spart);
    k2_mid<<<290, 256, 0, stream>>>(spart, qp_W1, qp_b1, sb, WqT, phiQ2s, Wf1T,
                                    phiWT, Wos, Wf2T, S_QP, S_SM, phiQ1T,
                                    phiQ_b1, Qmid);
    k3_proj<<<640, 256, 0, stream>>>(f_q, qpW1loT, WkT, WvT, sb, qp_W2, qp_b2, P,
                                     bk, bv, outP, outV, evb, kmb, vtb, Qmid, Wf1T,
                                     bf1, qscale, qmb);
    attn_mfma<<<1024, 256, 0, stream>>>(qmb, kmb, vtb, evb, Op16, Lp);
    k56_out<<<128, 256, 0, stream>>>(Op16, Lp, Wf2T, bf2, S_SM, outS);
}

// Round 10
// 180.793 us; speedup vs baseline: 1.0337x; 1.0154x over previous
//
#include <hip/hip_runtime.h>
#include <math.h>

// B=2, Lq=1024, C=256, H=W=64 -> Lk=4096, NC=2, NH=8, D=32.
// R10: 4 dispatches. k2 eliminated:
//  - Wf1T/Wf2T computed in k1 straight from fp32 inputs (gathered A-frags)
//  - sbias computed inline in k3's qp blocks (from k1's mean partials)
//  - phiQ1 + q-projection fused in one k3 block range (Qmid stays in LDS)
//  - k56 col-split x2 (128->256 blocks)
// attn: R9 transpose-free form (S^T=mfma(K,Q); P^T C-regs feed PV as B-frags;
// V kv-permuted & e-scaled; L via e-frag MFMA; kv-split x8).

#define LQ 1024
#define HW 4096
#define LOG2E 1.4426950408889634f

typedef __attribute__((ext_vector_type(8))) short short8;
typedef __attribute__((ext_vector_type(4))) float f32x4;
typedef unsigned short u16;

__device__ __forceinline__ u16 bf16r(float x) {
    unsigned int u = __float_as_uint(x);
    u = (u + 0x7FFFu + ((u >> 16) & 1u)) >> 16;
    return (u16)u;
}

__device__ __forceinline__ float b2f(u16 v) {
    return __uint_as_float((unsigned)v << 16);
}

__device__ __forceinline__ float ent2(float a, float b) {
    float m  = fmaxf(a, b);
    float e0 = expf(a - m), e1 = expf(b - m);
    float iz = 1.f / (e0 + e1);
    float p0 = fmaxf(e0 * iz, 1e-8f);
    float p1 = fmaxf(e1 * iz, 1e-8f);
    return -(p0 * logf(p0) + p1 * logf(p1));
}

typedef __attribute__((address_space(1))) const unsigned int gas_u32;
typedef __attribute__((address_space(3))) unsigned int las_u32;
__device__ __forceinline__ void glds16(const void* g, void* l) {
    __builtin_amdgcn_global_load_lds((gas_u32*)g, (las_u32*)l, 16, 0, 0);
}

// kv-permutation within a 32-group: p(16t + 4q2 + r) = 8*q2 + 4*t + r
__device__ __forceinline__ int kvperm(int l) {
    int w = l & 31;
    return (l & ~31) | (((w >> 2) & 3) << 3) | (((w >> 4) & 1) << 2) | (w & 3);
}

// ---- fused-weight GEMM, all-inline from fp32:
// out16[a*256+b] = sum_o G[o*256+a] * S[b*256+o]
// (A-frag gathered from G columns; B-frag straight rows of S.)
__device__ __forceinline__ void fuse_gemm(int bid, const float* __restrict__ G,
                                          const float* __restrict__ S,
                                          u16* __restrict__ out16) {
    const int wv = threadIdx.x >> 6, lane = threadIdx.x & 63;
    const int lm = lane & 15, quad = lane >> 4;
    const int row0 = (bid >> 1) * 32;          // a
    const int c0 = (bid & 1) * 128 + wv * 32;  // b
    short8 af[2][8];
#pragma unroll
    for (int s = 0; s < 2; ++s)
#pragma unroll
        for (int i = 0; i < 8; ++i) {
            short8 t;
#pragma unroll
            for (int j = 0; j < 8; ++j)
                t[j] = (short)bf16r(G[(size_t)(i * 32 + quad * 8 + j) * 256 +
                                      row0 + s * 16 + lm]);
            af[s][i] = t;
        }
#pragma unroll
    for (int j = 0; j < 2; ++j) {
        int b = c0 + j * 16 + lm;
        f32x4 acc[2];
        acc[0] = f32x4{0.f, 0.f, 0.f, 0.f};
        acc[1] = acc[0];
#pragma unroll
        for (int i = 0; i < 8; ++i) {
            const float* sp = S + (size_t)b * 256 + i * 32 + quad * 8;
            float4 f0 = *(const float4*)sp;
            float4 f1 = *(const float4*)(sp + 4);
            short8 bfv;
            bfv[0] = (short)bf16r(f0.x); bfv[1] = (short)bf16r(f0.y);
            bfv[2] = (short)bf16r(f0.z); bfv[3] = (short)bf16r(f0.w);
            bfv[4] = (short)bf16r(f1.x); bfv[5] = (short)bf16r(f1.y);
            bfv[6] = (short)bf16r(f1.z); bfv[7] = (short)bf16r(f1.w);
#pragma unroll
            for (int s = 0; s < 2; ++s)
                acc[s] = __builtin_amdgcn_mfma_f32_16x16x32_bf16(af[s][i], bfv,
                                                                 acc[s], 0, 0, 0);
        }
#pragma unroll
        for (int s = 0; s < 2; ++s)
#pragma unroll
            for (int r = 0; r < 4; ++r)
                out16[(size_t)(row0 + s * 16 + quad * 4 + r) * 256 + b] =
                    bf16r(acc[s][r]);
    }
}

// ======== K1: prep (386 blocks)
// [0,64) qpW1hi^T, [64,128) Wk^T, [128,192) Wv^T, [192,320) phiQ1^T (K=512),
// [320,336) Wf1T fusion, [336,352) Wf2T fusion, [352,354) bias_fuse,
// [354,386) mean partials.
__global__ __launch_bounds__(256) void k1_prep(
    const float* qpW1hi, const float* Wk, const float* Wv, const float* phiQ1,
    const float* Wq, const float* phiW, const float* phiQ2, const float* Wo,
    u16* qpW1loT, u16* WkT, u16* WvT, u16* phiQ1T, u16* Wf1T, u16* Wf2T,
    const float* pb2, const float* bq, const float* bo, const float* phib,
    float* bf1, float* bf2,
    const float* S_SM, float* spart) {
    __shared__ float tile[32][33];
    int bid = blockIdx.x;
    if (bid < 320) {  // transposes W[K,256] -> Wt[256,K] bf16
        const float* S; u16* D; int K;
        if (bid < 64)       { S = qpW1hi; D = qpW1loT; K = 256; }
        else if (bid < 128) { S = Wk; D = WkT; K = 256; bid -= 64; }
        else if (bid < 192) { S = Wv; D = WvT; K = 256; bid -= 128; }
        else                { S = phiQ1; D = phiQ1T; K = 512; bid -= 192; }
        int KT = K >> 5;
        int tk = bid % KT, tn = bid / KT;
        int cc = threadIdx.x & 31, rb = threadIdx.x >> 5;
#pragma unroll
        for (int i = 0; i < 4; ++i) {
            int rr = rb + i * 8;
            tile[rr][cc] = S[(size_t)(tk * 32 + rr) * 256 + tn * 32 + cc];
        }
        __syncthreads();
#pragma unroll
        for (int i = 0; i < 4; ++i) {
            int rr = rb + i * 8;
            D[(size_t)(tn * 32 + rr) * K + tk * 32 + cc] = bf16r(tile[cc][rr]);
        }
    } else if (bid < 336) {  // Wf1T[n][c] = sum_o phiQ2[c][o] * Wq[o][n]
        fuse_gemm(bid - 320, Wq, phiQ2, Wf1T);
    } else if (bid < 352) {  // Wf2T[n][d] = sum_o Wo[d][o] * phiW[o][n]
        fuse_gemm(bid - 336, phiW, Wo, Wf2T);
    } else if (bid < 354) {  // bias_fuse
        int n = threadIdx.x;
        if (bid == 352) {
            float a = bq[n];
            for (int c = 0; c < 256; ++c) a += pb2[c] * Wq[c * 256 + n];
            bf1[n] = a;
        } else {
            float a = phib[n];
            for (int c = 0; c < 256; ++c) a += bo[c] * phiW[c * 256 + n];
            bf2[n] = a;
        }
    } else {  // mean partials: 32 slabs of 64 rows
        int bi = bid - 354;
        int b = bi >> 4, l0 = (bi & 15) * 64;
        int c = threadIdx.x;
        const float* p = S_SM + (size_t)b * LQ * 256 + (size_t)l0 * 256 + c;
        float acc = 0.f;
#pragma unroll 8
        for (int l = 0; l < 64; ++l) acc += p[(size_t)l * 256];
        spart[bi * 256 + c] = acc;
    }
}

// ======== K3: proj (640 blocks)
// [0,512): fused qp+K+V (A from f_q; sbias computed inline from spart)
// [512,640): phiQ1 + q-projection fused (Qmid in LDS)
__global__ __launch_bounds__(256) void k3_proj(
    const float* __restrict__ f_q, const u16* __restrict__ Wqp,
    const u16* __restrict__ Wk, const u16* __restrict__ Wv,
    const float* __restrict__ spart, const float* __restrict__ qpW1,
    const float* __restrict__ qpb1, const float* __restrict__ qpW2,
    const float* __restrict__ qpb2, const float* __restrict__ P,
    const float* __restrict__ bk, const float* __restrict__ bv,
    float* __restrict__ outPhat, float* __restrict__ outV,
    u16* __restrict__ evb, u16* __restrict__ kmb, u16* __restrict__ vtb,
    const float* __restrict__ S_QP, const float* __restrict__ S_SM,
    const u16* __restrict__ phiQ1T, const float* __restrict__ phiQb1,
    const u16* __restrict__ Wf1T, const float* __restrict__ bf1,
    float qscale, u16* __restrict__ qmb) {
    int bid = blockIdx.x;
    const int wv = threadIdx.x >> 6, lane = threadIdx.x & 63;
    const int lm = lane & 15, quad = lane >> 4;
    if (bid >= 512) {  // ---- phiQ1 + q-proj fused: 16 rows per block
        __shared__ __align__(16) u16 qs[16][264];
        const int row0 = (bid - 512) * 16;
        short8 af[16];
#pragma unroll
        for (int i = 0; i < 16; ++i) {
            const float* src = (i < 8)
                ? (S_QP + (size_t)(row0 + lm) * 256 + i * 32 + quad * 8)
                : (S_SM + (size_t)(row0 + lm) * 256 + (i - 8) * 32 + quad * 8);
            float4 f0 = *(const float4*)src;
            float4 f1 = *(const float4*)(src + 4);
            short8 t;
            t[0] = (short)bf16r(f0.x); t[1] = (short)bf16r(f0.y);
            t[2] = (short)bf16r(f0.z); t[3] = (short)bf16r(f0.w);
            t[4] = (short)bf16r(f1.x); t[5] = (short)bf16r(f1.y);
            t[6] = (short)bf16r(f1.z); t[7] = (short)bf16r(f1.w);
            af[i] = t;
        }
#pragma unroll
        for (int j = 0; j < 4; ++j) {
            int n = wv * 64 + j * 16 + lm;
            float bvv = phiQb1[n];
            f32x4 acc = {bvv, bvv, bvv, bvv};
            const u16* wp = phiQ1T + (size_t)n * 512 + quad * 8;
#pragma unroll
            for (int i = 0; i < 16; ++i) {
                short8 bfv = *(const short8*)(wp + i * 32);
                acc = __builtin_amdgcn_mfma_f32_16x16x32_bf16(af[i], bfv, acc, 0, 0, 0);
            }
#pragma unroll
            for (int r = 0; r < 4; ++r)
                qs[quad * 4 + r][n] = bf16r(fmaxf(acc[r], 0.f));
        }
        __syncthreads();
        short8 aq[8];
#pragma unroll
        for (int i = 0; i < 8; ++i)
            aq[i] = *(const short8*)&qs[lm][i * 32 + quad * 8];
#pragma unroll
        for (int j = 0; j < 4; ++j) {
            int n = wv * 64 + j * 16 + lm;
            float bvv = bf1[n];
            f32x4 acc = {bvv, bvv, bvv, bvv};
            const u16* wp = Wf1T + (size_t)n * 256 + quad * 8;
#pragma unroll
            for (int i = 0; i < 8; ++i) {
                short8 bfv = *(const short8*)(wp + i * 32);
                acc = __builtin_amdgcn_mfma_f32_16x16x32_bf16(aq[i], bfv, acc, 0, 0, 0);
            }
#pragma unroll
            for (int r = 0; r < 4; ++r)
                qmb[(size_t)(row0 + quad * 4 + r) * 256 + n] = bf16r(acc[r] * qscale);
        }
        return;
    }
    // ---- fused qp + K + V
    __shared__ float smean_s[256];
    __shared__ float sb_s[256];
    __shared__ float red[4][16][2];
    __shared__ float evl[16];
    const int row0 = bid * 16;
    const int b = row0 >> 12;
    {   // inline sbias: smean from partials, then dot vs qpW1 lo half
        int o = threadIdx.x;
        float sm = 0.f;
#pragma unroll
        for (int p = 0; p < 16; ++p) sm += spart[(b * 16 + p) * 256 + o];
        smean_s[o] = sm * (1.f / 1024.f);
        __syncthreads();
        float a = qpb1[o];
        for (int c = 0; c < 256; ++c) a += smean_s[c] * qpW1[(size_t)c * 256 + o];
        sb_s[o] = a;
        __syncthreads();
    }
    const int l = (row0 & 4095) + lm;
    const float* fb = f_q + (size_t)b * 256 * HW + l;
    short8 af[8];
#pragma unroll
    for (int i = 0; i < 8; ++i) {
        short8 t;
#pragma unroll
        for (int j = 0; j < 8; ++j)
            t[j] = (short)bf16r(fb[(size_t)(i * 32 + quad * 8 + j) * HW]);
        af[i] = t;
    }
    // --- qp part
    float c0p[4] = {0.f, 0.f, 0.f, 0.f}, c1p[4] = {0.f, 0.f, 0.f, 0.f};
#pragma unroll
    for (int j = 0; j < 4; ++j) {
        int n = wv * 64 + j * 16 + lm;
        float bv2 = sb_s[n];
        f32x4 acc = {bv2, bv2, bv2, bv2};
        const u16* wp = Wqp + (size_t)n * 256 + quad * 8;
#pragma unroll
        for (int i = 0; i < 8; ++i) {
            short8 bfv = *(const short8*)(wp + i * 32);
            acc = __builtin_amdgcn_mfma_f32_16x16x32_bf16(af[i], bfv, acc, 0, 0, 0);
        }
        float w20 = qpW2[n * 2], w21 = qpW2[n * 2 + 1];
#pragma unroll
        for (int r = 0; r < 4; ++r) {
            float hh = fmaxf(acc[r], 0.f);
            c0p[r] += hh * w20;
            c1p[r] += hh * w21;
        }
    }
#pragma unroll
    for (int m = 1; m < 16; m <<= 1) {
#pragma unroll
        for (int r = 0; r < 4; ++r) {
            c0p[r] += __shfl_xor(c0p[r], m);
            c1p[r] += __shfl_xor(c1p[r], m);
        }
    }
    if (lm == 0) {
#pragma unroll
        for (int r = 0; r < 4; ++r) {
            red[wv][quad * 4 + r][0] = c0p[r];
            red[wv][quad * 4 + r][1] = c1p[r];
        }
    }
    __syncthreads();
    int t = threadIdx.x;
    if (t < 16) {
        float ph0 = red[0][t][0] + red[1][t][0] + red[2][t][0] + red[3][t][0] + qpb2[0];
        float ph1 = red[0][t][1] + red[1][t][1] + red[2][t][1] + red[3][t][1] + qpb2[1];
        int hw = (row0 + t) & 4095;
        float Vv = ent2(ph0, ph1) -
                   ent2(P[(size_t)b * 8192 + hw], P[(size_t)b * 8192 + 4096 + hw]);
        outPhat[(size_t)b * 8192 + hw] = ph0;
        outPhat[(size_t)b * 8192 + 4096 + hw] = ph1;
        outV[b * 4096 + hw] = Vv;
        float ev = expf(Vv);
        evl[t] = ev;
        evb[b * HW + kvperm(hw)] = bf16r(ev);
    }
    // --- K part
#pragma unroll
    for (int j = 0; j < 4; ++j) {
        int n = wv * 64 + j * 16 + lm;
        float bv2 = bk[n];
        f32x4 acc = {bv2, bv2, bv2, bv2};
        const u16* wp = Wk + (size_t)n * 256 + quad * 8;
#pragma unroll
        for (int i = 0; i < 8; ++i) {
            short8 bfv = *(const short8*)(wp + i * 32);
            acc = __builtin_amdgcn_mfma_f32_16x16x32_bf16(af[i], bfv, acc, 0, 0, 0);
        }
#pragma unroll
        for (int r = 0; r < 4; ++r)
            kmb[(size_t)(row0 + quad * 4 + r) * 256 + n] = bf16r(acc[r]);
    }
    __syncthreads();  // evl visible to all
    // --- V part: scale rows by e, store [b,h,d][kv'] with kvperm
#pragma unroll
    for (int j = 0; j < 4; ++j) {
        int n = wv * 64 + j * 16 + lm;
        float bv2 = bv[n];
        f32x4 acc = {bv2, bv2, bv2, bv2};
        const u16* wp = Wv + (size_t)n * 256 + quad * 8;
#pragma unroll
        for (int i = 0; i < 8; ++i) {
            short8 bfv = *(const short8*)(wp + i * 32);
            acc = __builtin_amdgcn_mfma_f32_16x16x32_bf16(af[i], bfv, acc, 0, 0, 0);
        }
#pragma unroll
        for (int r = 0; r < 4; ++r) {
            int row = row0 + quad * 4 + r;
            int l2 = row & 4095;
            int pos = kvperm(l2);
            float vvv = acc[r] * evl[quad * 4 + r];
            vtb[((size_t)((b * 8 + (n >> 5)) * 32 + (n & 31))) * HW + pos] = bf16r(vvv);
        }
    }
}

// ======== K4: MFMA flash attention (R9 transpose-free form, unchanged)
__global__ __launch_bounds__(256) void attn_mfma(const u16* __restrict__ qm,
                                                 const u16* __restrict__ km,
                                                 const u16* __restrict__ vt,
                                                 const u16* __restrict__ evb,
                                                 u16* __restrict__ Op,
                                                 float* __restrict__ Lp) {
    __shared__ __align__(16) u16 Kst[3][2048];   // [kv 64][d 32]
    __shared__ __align__(16) u16 Vst[3][2048];   // [d 32][kv' 64] seg-rotated
    const int blk = blockIdx.x;   // 1024 = 2b * 8qt * 8sp * 8h
    const int h = blk & 7, sp = (blk >> 3) & 7, qt = (blk >> 6) & 7, b = blk >> 9;
    const int tid = threadIdx.x;
    const int wv = tid >> 6, lane = tid & 63;
    const int lm = lane & 15, quad = lane >> 4;
    const int q0 = qt * 128 + wv * 32;
    short8 qf[2];
#pragma unroll
    for (int s = 0; s < 2; ++s)
        qf[s] = *(const short8*)(qm + ((size_t)(b * LQ + q0 + s * 16 + lm)) * 256 +
                                 h * 32 + quad * 8);
    const u16* kbh = km + (size_t)b * HW * 256 + h * 32;
    const u16* vbh = vt + (size_t)(b * 8 + h) * 32 * HW;
    const u16* eb = evb + (size_t)b * HW;
    const int krow = tid >> 2, kseg = tid & 3;
    const int vd = tid >> 3, vp = tid & 7, vs = (vp - vd) & 7;
    const int kv_lo = sp * 512;
    const f32x4 z4 = {0.f, 0.f, 0.f, 0.f};
    f32x4 o[2][2] = {{z4, z4}, {z4, z4}};  // [qfrag][dtile], O^T C-layout
    f32x4 lr[2] = {z4, z4};
    glds16(kbh + (size_t)(kv_lo + krow) * 256 + kseg * 8, &Kst[0][wv * 512]);
    glds16(vbh + (size_t)vd * HW + kv_lo + vs * 8, &Vst[0][wv * 512]);
    glds16(kbh + (size_t)(kv_lo + 64 + krow) * 256 + kseg * 8, &Kst[1][wv * 512]);
    glds16(vbh + (size_t)vd * HW + kv_lo + 64 + vs * 8, &Vst[1][wv * 512]);
    const int vss = (quad + lm) & 7;
    for (int c = 0; c < 8; ++c) {
        __syncthreads();
        if (c + 2 < 8) {
            int kc2 = kv_lo + (c + 2) * 64, ib = (c + 2) % 3;
            glds16(kbh + (size_t)(kc2 + krow) * 256 + kseg * 8, &Kst[ib][wv * 512]);
            glds16(vbh + (size_t)vd * HW + kc2 + vs * 8, &Vst[ib][wv * 512]);
        }
        const int idx = c % 3;
        const int kc = kv_lo + c * 64;
        const u16* kbuf = Kst[idx];
        const u16* vbuf = Vst[idx];
        f32x4 st[2][4];
#pragma unroll
        for (int tt = 0; tt < 4; ++tt) {
            short8 kf = *(const short8*)(kbuf + (tt * 16 + lm) * 32 + quad * 8);
            st[0][tt] = __builtin_amdgcn_mfma_f32_16x16x32_bf16(kf, qf[0], z4, 0, 0, 0);
            st[1][tt] = __builtin_amdgcn_mfma_f32_16x16x32_bf16(kf, qf[1], z4, 0, 0, 0);
        }
        short8 pf[2][2];
#pragma unroll
        for (int s = 0; s < 2; ++s)
#pragma unroll
            for (int c2 = 0; c2 < 2; ++c2) {
                short8 pk;
#pragma unroll
                for (int j = 0; j < 8; ++j) {
                    float pv = __builtin_amdgcn_exp2f(st[s][c2 * 2 + (j >> 2)][j & 3]);
                    pk[j] = (short)(__float_as_uint(pv) >> 16);
                }
                pf[s][c2] = pk;
            }
#pragma unroll
        for (int c2 = 0; c2 < 2; ++c2) {
            short8 ef = *(const short8*)(eb + kc + c2 * 32 + quad * 8);
            short8 vf0 = *(const short8*)(vbuf + lm * 64 + ((c2 * 4 + vss) & 7) * 8);
            short8 vf1 = *(const short8*)(vbuf + (16 + lm) * 64 + ((c2 * 4 + vss) & 7) * 8);
#pragma unroll
            for (int s = 0; s < 2; ++s) {
                lr[s] = __builtin_amdgcn_mfma_f32_16x16x32_bf16(ef, pf[s][c2], lr[s], 0, 0, 0);
                o[s][0] = __builtin_amdgcn_mfma_f32_16x16x32_bf16(vf0, pf[s][c2], o[s][0], 0, 0, 0);
                o[s][1] = __builtin_amdgcn_mfma_f32_16x16x32_bf16(vf1, pf[s][c2], o[s][1], 0, 0, 0);
            }
        }
    }
#pragma unroll
    for (int s = 0; s < 2; ++s) {
        int qg = q0 + s * 16 + lm;
        size_t rbase = (size_t)sp * 16384 + (size_t)(b * 8 + h) * LQ + qg;
#pragma unroll
        for (int dt = 0; dt < 2; ++dt)
#pragma unroll
            for (int r = 0; r < 4; ++r)
                Op[rbase * 32 + dt * 16 + quad * 4 + r] = bf16r(o[s][dt][r]);
        if (quad == 0) Lp[rbase] = lr[s][0];
    }
}

// ======== K56: combine + final GEMM, col-split x2 (256 blocks).
__global__ __launch_bounds__(256) void k56_out(const u16* __restrict__ Op,
                                               const float* __restrict__ Lp,
                                               const u16* __restrict__ Wf2T,
                                               const float* __restrict__ bf2,
                                               const float* __restrict__ S_SM,
                                               float* __restrict__ outS) {
    __shared__ __align__(16) u16 comb[16][264];
    const int bid = blockIdx.x;
    const int row0 = (bid >> 1) * 16;
    const int nbase = (bid & 1) * 128;
    const int t = threadIdx.x;
    {  // phase A: thread = (row, 16-ch group); fills all 256 ch
        int rowi = t >> 4, chg = (t & 15) * 16;
        int grow = row0 + rowi;
        int b = grow >> 10, q = grow & 1023;
        int hh = chg >> 5, d0 = chg & 31;
        const u16* ob = Op + ((size_t)(b * 8 + hh) * 1024 + q) * 32 + d0;
        float a[16];
#pragma unroll
        for (int j = 0; j < 16; ++j) a[j] = 0.f;
        float LS = 0.f;
#pragma unroll
        for (int s = 0; s < 8; ++s) {
            short8 v0 = *(const short8*)(ob + (size_t)s * 16384 * 32);
            short8 v1 = *(const short8*)(ob + (size_t)s * 16384 * 32 + 8);
#pragma unroll
            for (int j = 0; j < 8; ++j) {
                a[j] += b2f((u16)v0[j]);
                a[8 + j] += b2f((u16)v1[j]);
            }
            LS += Lp[(size_t)s * 16384 + (size_t)(b * 8 + hh) * 1024 + q];
        }
        float il = 1.f / LS;
#pragma unroll
        for (int g = 0; g < 4; ++g) {
            ushort4 pk = {bf16r(a[g * 4] * il), bf16r(a[g * 4 + 1] * il),
                          bf16r(a[g * 4 + 2] * il), bf16r(a[g * 4 + 3] * il)};
            *(ushort4*)&comb[rowi][chg + g * 4] = pk;
        }
    }
    __syncthreads();
    const int wv = t >> 6, lane = t & 63;
    const int lm = lane & 15, quad = lane >> 4;
    short8 af[8];
#pragma unroll
    for (int i = 0; i < 8; ++i)
        af[i] = *(const short8*)&comb[lm][i * 32 + quad * 8];
    f32x4 acc[2];
#pragma unroll
    for (int j = 0; j < 2; ++j) {
        int n = nbase + wv * 32 + j * 16 + lm;
        float bvv = bf2[n];
        acc[j] = f32x4{bvv, bvv, bvv, bvv};
        const u16* wp = Wf2T + (size_t)n * 256 + quad * 8;
#pragma unroll
        for (int i = 0; i < 8; ++i) {
            short8 bfv = *(const short8*)(wp + i * 32);
            acc[j] = __builtin_amdgcn_mfma_f32_16x16x32_bf16(af[i], bfv, acc[j], 0, 0, 0);
        }
    }
#pragma unroll
    for (int j = 0; j < 2; ++j) {
        int n = nbase + wv * 32 + j * 16 + lm;
#pragma unroll
        for (int r = 0; r < 4; ++r) {
            int row = row0 + quad * 4 + r;
            outS[(size_t)row * 256 + n] = S_SM[(size_t)row * 256 + n] - acc[j][r];
        }
    }
}

extern "C" void kernel_launch(void* const* d_in, const int* in_sizes, int n_in,
                              void* d_out, int out_size, void* d_ws, size_t ws_size,
                              hipStream_t stream) {
    const float* S_QP = (const float*)d_in[0];
    const float* S_SM = (const float*)d_in[1];
    const float* f_q = (const float*)d_in[2];
    const float* P = (const float*)d_in[3];
    const float* qp_W1 = (const float*)d_in[4];
    const float* qp_b1 = (const float*)d_in[5];
    const float* qp_W2 = (const float*)d_in[6];
    const float* qp_b2 = (const float*)d_in[7];
    const float* phiQ_W1 = (const float*)d_in[8];
    const float* phiQ_b1 = (const float*)d_in[9];
    const float* phiQ_W2 = (const float*)d_in[10];
    const float* phiQ_b2 = (const float*)d_in[11];
    const float* Wq = (const float*)d_in[12];
    const float* bq = (const float*)d_in[13];
    const float* Wk = (const float*)d_in[14];
    const float* bk = (const float*)d_in[15];
    const float* Wv = (const float*)d_in[16];
    const float* bv = (const float*)d_in[17];
    const float* Wo = (const float*)d_in[18];
    const float* bo = (const float*)d_in[19];
    const float* phi_W = (const float*)d_in[20];
    const float* phi_b = (const float*)d_in[21];

    float* out = (float*)d_out;
    float* outS = out;            // [2,1024,256]
    float* outP = out + 524288;   // [2,2,64,64]
    float* outV = out + 540672;   // [2,1,64,64]

    float* spart = (float*)d_ws;           // 8192
    float* Lp = spart + 8192;              // 131072
    float* bf1 = Lp + 131072;              // 256
    float* bf2 = bf1 + 256;                // 256
    u16* qpW1loT = (u16*)(bf2 + 256);      // 65536
    u16* WkT = qpW1loT + 65536;
    u16* WvT = WkT + 65536;
    u16* phiQ1T = WvT + 65536;             // 131072 (256x512)
    u16* Wf1T = phiQ1T + 131072;
    u16* Wf2T = Wf1T + 65536;
    u16* evb = Wf2T + 65536;               // 8192 (bf16, kv-permuted)
    u16* qmb = evb + 8192;                 // 524288
    u16* kmb = qmb + 524288;               // 2097152
    u16* vtb = kmb + 2097152;              // 2097152 (V^T * e, kv-permuted)
    u16* Op16 = vtb + 2097152;             // 4194304

    const float qscale = 0.17677669529663687f * LOG2E;

    k1_prep<<<386, 256, 0, stream>>>(qp_W1 + 65536, Wk, Wv, phiQ_W1, Wq, phi_W,
                                     phiQ_W2, Wo, qpW1loT, WkT, WvT, phiQ1T,
                                     Wf1T, Wf2T, phiQ_b2, bq, bo, phi_b,
                                     bf1, bf2, S_SM, spart);
    k3_proj<<<640, 256, 0, stream>>>(f_q, qpW1loT, WkT, WvT, spart, qp_W1, qp_b1,
                                     qp_W2, qp_b2, P, bk, bv, outP, outV, evb,
                                     kmb, vtb, S_QP, S_SM, phiQ1T, phiQ_b1,
                                     Wf1T, bf1, qscale, qmb);
    attn_mfma<<<1024, 256, 0, stream>>>(qmb, kmb, vtb, evb, Op16, Lp);
    k56_out<<<256, 256, 0, stream>>>(Op16, Lp, Wf2T, bf2, S_SM, outS);
}